// Round 1
// baseline (827.650 us; speedup 1.0000x reference)
//
#include <hip/hip_runtime.h>

// Problem constants
constexpr int Bb = 4, Hh = 32, Wd = 256, Cc = 96;
constexpr int DI = 192, Nn = 16, Rr = 6, Kk = 2;
constexpr int LL = Hh * Wd;          // 8192
constexpr int ROWS = Bb * LL;        // 32768
constexpr int PROJ_C = 40;           // padded proj row: [0..5]=dts, [8..23]=B, [24..39]=C
constexpr int G = 32;                // scan chunks
constexpr int CH = LL / G;           // 256 steps per chunk

static __device__ __forceinline__ float sigmoidf_(float v) {
  return 1.f / (1.f + __expf(-v));
}
static __device__ __forceinline__ float softplusf_(float v) {
  return v > 20.f ? v : log1pf(__expf(v));
}

// ---------------------------------------------------------------------------
// Kernel 1: xz = x @ W_in^T  (32768 x 384, K=96). 64x64 block tile, 4x4 reg
// tile with strided lane mapping (rows = ty+16*rr, cols = tx+16*cc) to keep
// LDS float4 reads 2-way-or-less on banks. cols<192 -> xc, else -> z.
// ---------------------------------------------------------------------------
__global__ __launch_bounds__(256) void k_xz(const float* __restrict__ x,
                                            const float* __restrict__ Win,
                                            float* __restrict__ xc,
                                            float* __restrict__ zbuf) {
  __shared__ float xt[24][66][4];  // [k4][row][j], padded row dim
  __shared__ float wt[24][66][4];  // [k4][col][j]
  const int row0 = blockIdx.x * 64;
  const int col0 = blockIdx.y * 64;
  const int tid = threadIdx.x;

  for (int idx = tid; idx < 64 * 96; idx += 256) {
    int r = idx / 96, kkk = idx % 96;
    xt[kkk >> 2][r][kkk & 3] = x[(size_t)(row0 + r) * 96 + kkk];
    wt[kkk >> 2][r][kkk & 3] = Win[(size_t)(col0 + r) * 96 + kkk];
  }
  __syncthreads();

  const int tx = tid & 15, ty = tid >> 4;
  float acc[4][4] = {};
  for (int k4 = 0; k4 < 24; ++k4) {
    float4 a4[4], b4[4];
#pragma unroll
    for (int i = 0; i < 4; ++i) {
      a4[i] = *(const float4*)&xt[k4][ty + 16 * i][0];
      b4[i] = *(const float4*)&wt[k4][tx + 16 * i][0];
    }
#pragma unroll
    for (int r = 0; r < 4; ++r)
#pragma unroll
      for (int c = 0; c < 4; ++c) {
        acc[r][c] = fmaf(a4[r].x, b4[c].x, acc[r][c]);
        acc[r][c] = fmaf(a4[r].y, b4[c].y, acc[r][c]);
        acc[r][c] = fmaf(a4[r].z, b4[c].z, acc[r][c]);
        acc[r][c] = fmaf(a4[r].w, b4[c].w, acc[r][c]);
      }
  }

#pragma unroll
  for (int r = 0; r < 4; ++r) {
    int R = row0 + ty + 16 * r;
#pragma unroll
    for (int c = 0; c < 4; ++c) {
      int col = col0 + tx + 16 * c;
      if (col < DI)
        xc[(size_t)R * DI + col] = acc[r][c];
      else
        zbuf[(size_t)R * DI + (col - DI)] = acc[r][c];
    }
  }
}

// ---------------------------------------------------------------------------
// Kernel 2: depthwise 3x3 conv (SAME) + bias + SiLU.  xc,xf layout [b][l][d].
// ---------------------------------------------------------------------------
__global__ __launch_bounds__(256) void k_conv(const float* __restrict__ xc,
                                              const float* __restrict__ cw,
                                              const float* __restrict__ cbias,
                                              float* __restrict__ xf) {
  int gid = blockIdx.x * 256 + threadIdx.x;  // = (b*LL + l)*DI + d
  int d = gid % DI;
  int bl = gid / DI;
  int l = bl % LL;
  int b = bl / LL;
  int hh = l >> 8, ww = l & 255;
  float acc = 0.f;
#pragma unroll
  for (int dh = -1; dh <= 1; ++dh) {
    int h2 = hh + dh;
    if (h2 < 0 || h2 >= Hh) continue;
#pragma unroll
    for (int dw = -1; dw <= 1; ++dw) {
      int w2 = ww + dw;
      if (w2 < 0 || w2 >= Wd) continue;
      acc = fmaf(xc[((size_t)b * LL + (h2 << 8) + w2) * DI + d],
                 cw[d * 9 + (dh + 1) * 3 + (dw + 1)], acc);
    }
  }
  float v = acc + cbias[d];
  xf[gid] = v * sigmoidf_(v);
}

// ---------------------------------------------------------------------------
// Kernel 3: x_dbl[b,k,c,l] = sum_d xf[b,l,d] * xpw[k,c,d], stored in padded
// proj rows [b][k][l][40]: off = c<6 ? c : c+2  (B at 8..23, C at 24..39,
// both 16B aligned for float4 reads in the scan).
// ---------------------------------------------------------------------------
__global__ __launch_bounds__(256) void k_proj(const float* __restrict__ xf,
                                              const float* __restrict__ xpw,
                                              float* __restrict__ proj) {
  __shared__ float xs[32][193];
  const int bidx = blockIdx.x;  // b*(LL/32) + tile
  const int b = bidx >> 8;
  const int l0 = (bidx & 255) * 32;
  const int tid = threadIdx.x;

  for (int idx = tid; idx < 32 * DI; idx += 256) {
    int l = idx / DI, d = idx % DI;
    xs[l][d] = xf[((size_t)b * LL + l0 + l) * DI + d];
  }
  __syncthreads();

  const int lt = tid & 31, j = tid >> 5;
  for (int kc = j; kc < 2 * 38; kc += 8) {
    int k = kc / 38, c = kc % 38;
    const float* wp = xpw + (size_t)(k * 38 + c) * DI;
    float acc = 0.f;
#pragma unroll 8
    for (int d = 0; d < DI; ++d) acc = fmaf(xs[lt][d], wp[d], acc);
    int off = c < 6 ? c : c + 2;
    proj[((size_t)(b * Kk + k) * LL + l0 + lt) * PROJ_C + off] = acc;
  }
}

// ---------------------------------------------------------------------------
// Scan kernels. Group = (b,k,d,chunk): 4 lanes x 4 states (n = sub*4+i).
// PASS 1: h from 0, record h_end and P = exp(A*sum(delta)).
// PASS 3: h from hinit, emit y (16-lane... 4-lane reduce + D term), write
//         y[b][k][d][l] at ORIGINAL l (reversal folded in for k=1).
// ---------------------------------------------------------------------------
template <int PASS>
__global__ __launch_bounds__(256) void k_scan(
    const float* __restrict__ proj, const float* __restrict__ xf,
    const float* __restrict__ dtw_, const float* __restrict__ dtb_,
    const float* __restrict__ Alog, const float* __restrict__ Dsv,
    const float* __restrict__ hinit, float* __restrict__ hend,
    float* __restrict__ Pst, float* __restrict__ yout) {
  const int tid = threadIdx.x;
  const int sub = tid & 3, gi = tid >> 2;  // gi 0..63
  int rest = blockIdx.x;
  const int dt3 = rest % 3;  rest /= 3;
  const int g = rest % G;    rest /= G;
  const int k = rest & 1;
  const int b = rest >> 1;
  const int d = dt3 * 64 + gi;
  const int kd = k * DI + d;

  float w6[6];
#pragma unroll
  for (int r = 0; r < 6; ++r) w6[r] = dtw_[kd * 6 + r];
  const float bias = dtb_[kd];
  float A[4];
#pragma unroll
  for (int i = 0; i < 4; ++i) A[i] = -__expf(Alog[kd * 16 + sub * 4 + i]);

  const size_t gidx =
      (((size_t)((b * Kk + k) * G + g)) * DI + d) * Nn + sub * 4;
  float h[4];
  if (PASS == 1) {
    h[0] = h[1] = h[2] = h[3] = 0.f;
  } else {
    float4 h4 = *(const float4*)&hinit[gidx];
    h[0] = h4.x; h[1] = h4.y; h[2] = h4.z; h[3] = h4.w;
  }
  const float Dv = (PASS == 3) ? Dsv[kd] : 0.f;

  const float* projb = proj + (size_t)(b * Kk + k) * LL * PROJ_C;
  const float* xfb = xf + (size_t)b * LL * DI + d;
  const size_t ybase = ((size_t)(b * Kk + k) * DI + d) * LL;

  float dsum = 0.f, ybuf = 0.f;
  const int tau0 = g * CH;
#pragma unroll 4
  for (int t = 0; t < CH; ++t) {
    const int tau = tau0 + t;
    const int l = k ? (LL - 1 - tau) : tau;
    const float* pr = projb + (size_t)l * PROJ_C;
    float draw = bias;
#pragma unroll
    for (int r = 0; r < 6; ++r) draw = fmaf(pr[r], w6[r], draw);
    const float delta = softplusf_(draw);
    const float u = xfb[(size_t)l * DI];
    const float4 Bv = *(const float4*)(pr + 8 + sub * 4);
    const float du = delta * u;
    if (PASS == 1) {
#pragma unroll
      for (int i = 0; i < 4; ++i)
        h[i] = fmaf(__expf(delta * A[i]), h[i], du * ((const float*)&Bv)[i]);
      dsum += delta;
    } else {
      const float4 Cv = *(const float4*)(pr + 24 + sub * 4);
      float yp = 0.f;
#pragma unroll
      for (int i = 0; i < 4; ++i) {
        h[i] = fmaf(__expf(delta * A[i]), h[i], du * ((const float*)&Bv)[i]);
        yp = fmaf(h[i], ((const float*)&Cv)[i], yp);
      }
      yp += __shfl_xor(yp, 1, 64);
      yp += __shfl_xor(yp, 2, 64);
      const float yt = fmaf(u, Dv, yp);
      ybuf = ((t & 3) == sub) ? yt : ybuf;
      if ((t & 3) == 3) {
        const int taup = (tau & ~3) + sub;
        const int lp = k ? (LL - 1 - taup) : taup;
        yout[ybase + lp] = ybuf;  // 4 lanes -> 16B contiguous
      }
    }
  }
  if (PASS == 1) {
    float4 hv = make_float4(h[0], h[1], h[2], h[3]);
    float4 pv = make_float4(__expf(A[0] * dsum), __expf(A[1] * dsum),
                            __expf(A[2] * dsum), __expf(A[3] * dsum));
    *(float4*)&hend[gidx] = hv;
    *(float4*)&Pst[gidx] = pv;
  }
}

// Pass 2: combine chunks sequentially per (b,k,d,n). hinit[g] = state at
// chunk start; carry' = P[g]*carry + hend[g].
__global__ __launch_bounds__(256) void k_scan2(const float* __restrict__ hend,
                                               const float* __restrict__ Pst,
                                               float* __restrict__ hini) {
  int idx = blockIdx.x * 256 + threadIdx.x;  // (bk*DI + d)*16 + n
  int n = idx & 15;
  int rem = idx >> 4;
  int d = rem % DI;
  int bk = rem / DI;
  float carry = 0.f;
  for (int g = 0; g < G; ++g) {
    size_t a = (((size_t)(bk * G + g)) * DI + d) * Nn + n;
    float hv = hend[a], pv = Pst[a];
    hini[a] = carry;
    carry = fmaf(pv, carry, hv);
  }
}

// ---------------------------------------------------------------------------
// Kernel 7: out[b,l,c] = sum_d (y0+y1)[b,d,l] * silu(z[b,l,d]) * Wout[c,d]
// Transpose y through LDS; staged coalesced output write.
// ---------------------------------------------------------------------------
__global__ __launch_bounds__(256) void k_out(const float* __restrict__ y,
                                             const float* __restrict__ zbuf,
                                             const float* __restrict__ Wout,
                                             float* __restrict__ out) {
  __shared__ float zt[32][193];
  __shared__ float mt[DI][33];
  const int bidx = blockIdx.x;
  const int b = bidx >> 8;
  const int l0 = (bidx & 255) * 32;
  const int tid = threadIdx.x;

  for (int idx = tid; idx < 32 * DI; idx += 256) {
    int l = idx / DI, d = idx % DI;
    zt[l][d] = zbuf[((size_t)b * LL + l0 + l) * DI + d];
  }
  __syncthreads();

  for (int idx = tid; idx < DI * 32; idx += 256) {
    int d = idx >> 5, l = idx & 31;
    size_t y0i = ((size_t)(b * Kk + 0) * DI + d) * LL + l0 + l;
    size_t y1i = ((size_t)(b * Kk + 1) * DI + d) * LL + l0 + l;
    float yv = y[y0i] + y[y1i];
    float zv = zt[l][d];
    mt[d][l] = yv * (zv * sigmoidf_(zv));
  }
  __syncthreads();

  const int lt = tid & 31, j = tid >> 5;
  float res[12];
#pragma unroll
  for (int ci = 0; ci < 12; ++ci) {
    int c = j + ci * 8;
    const float* wp = Wout + (size_t)c * DI;
    float acc = 0.f;
#pragma unroll 8
    for (int d = 0; d < DI; ++d) acc = fmaf(mt[d][lt], wp[d], acc);
    res[ci] = acc;
  }
  __syncthreads();
#pragma unroll
  for (int ci = 0; ci < 12; ++ci) zt[lt][j + ci * 8] = res[ci];
  __syncthreads();
  for (int idx = tid; idx < 32 * 96; idx += 256) {
    int l = idx / 96, c = idx % 96;
    out[((size_t)b * LL + l0 + l) * 96 + c] = zt[l][c];
  }
}

// ---------------------------------------------------------------------------
extern "C" void kernel_launch(void* const* d_in, const int* in_sizes, int n_in,
                              void* d_out, int out_size, void* d_ws,
                              size_t ws_size, hipStream_t stream) {
  const float* x    = (const float*)d_in[0];
  const float* Win  = (const float*)d_in[1];
  const float* cw   = (const float*)d_in[2];
  const float* cb   = (const float*)d_in[3];
  const float* xpw  = (const float*)d_in[4];
  const float* dtw  = (const float*)d_in[5];
  const float* dtb  = (const float*)d_in[6];
  const float* Alog = (const float*)d_in[7];
  const float* Dsv  = (const float*)d_in[8];
  const float* Wout = (const float*)d_in[9];
  float* out = (float*)d_out;

  float* ws = (float*)d_ws;
  size_t o = 0;
  float* zbuf = ws + o;  o += (size_t)ROWS * DI;                 // 25.2 MB
  float* xf   = ws + o;  o += (size_t)ROWS * DI;                 // 25.2 MB
  float* proj = ws + o;  o += (size_t)Bb * Kk * LL * PROJ_C;     // 10.5 MB
  const size_t hsz = (size_t)Bb * Kk * G * DI * Nn;              // 786432
  float* hend = ws + o;  o += hsz;
  float* Pst  = ws + o;  o += hsz;
  float* hini = ws + o;  o += hsz;
  float* y    = ws + o;  o += (size_t)Bb * Kk * DI * LL;         // 50.3 MB
  float* xc   = y;  // alias: xc dead after conv, before y is written

  k_xz<<<dim3(ROWS / 64, 6), 256, 0, stream>>>(x, Win, xc, zbuf);
  k_conv<<<dim3((ROWS * DI) / 256), 256, 0, stream>>>(xc, cw, cb, xf);
  k_proj<<<dim3(Bb * (LL / 32)), 256, 0, stream>>>(xf, xpw, proj);
  k_scan<1><<<dim3(Bb * Kk * G * 3), 256, 0, stream>>>(
      proj, xf, dtw, dtb, Alog, Dsv, nullptr, hend, Pst, nullptr);
  k_scan2<<<dim3((Bb * Kk * DI * Nn) / 256), 256, 0, stream>>>(hend, Pst,
                                                               hini);
  k_scan<3><<<dim3(Bb * Kk * G * 3), 256, 0, stream>>>(
      proj, xf, dtw, dtb, Alog, Dsv, hini, nullptr, nullptr, y);
  k_out<<<dim3(Bb * (LL / 32)), 256, 0, stream>>>(y, zbuf, Wout, out);
}

// Round 2
// 500.059 us; speedup vs baseline: 1.6551x; 1.6551x over previous
//
#include <hip/hip_runtime.h>

// Problem constants
constexpr int Bb = 4, Hh = 32, Wd = 256, Cc = 96;
constexpr int DI = 192, Nn = 16, Rr = 6, Kk = 2;
constexpr int LL = Hh * Wd;          // 8192
constexpr int ROWS = Bb * LL;        // 32768
constexpr int PROJ_C = 40;           // [0..5]=dts, pad, [8..23]=B, [24..39]=C
constexpr int G = 64;                // scan chunks
constexpr int CH = LL / G;           // 128 steps per chunk

static __device__ __forceinline__ float sigmoidf_(float v) {
  return 1.f / (1.f + __expf(-v));
}
static __device__ __forceinline__ float softplusf_(float v) {
  return v > 20.f ? v : __logf(1.f + __expf(v));
}

// ---------------------------------------------------------------------------
// Kernel 1: xz = x @ W_in^T  (32768 x 384, K=96). 64x64 tile, 4x4 reg tile.
// ---------------------------------------------------------------------------
__global__ __launch_bounds__(256) void k_xz(const float* __restrict__ x,
                                            const float* __restrict__ Win,
                                            float* __restrict__ xc,
                                            float* __restrict__ zbuf) {
  __shared__ float xt[24][66][4];
  __shared__ float wt[24][66][4];
  const int row0 = blockIdx.x * 64;
  const int col0 = blockIdx.y * 64;
  const int tid = threadIdx.x;

  for (int idx = tid; idx < 64 * 96; idx += 256) {
    int r = idx / 96, kkk = idx % 96;
    xt[kkk >> 2][r][kkk & 3] = x[(size_t)(row0 + r) * 96 + kkk];
    wt[kkk >> 2][r][kkk & 3] = Win[(size_t)(col0 + r) * 96 + kkk];
  }
  __syncthreads();

  const int tx = tid & 15, ty = tid >> 4;
  float acc[4][4] = {};
  for (int k4 = 0; k4 < 24; ++k4) {
    float4 a4[4], b4[4];
#pragma unroll
    for (int i = 0; i < 4; ++i) {
      a4[i] = *(const float4*)&xt[k4][ty + 16 * i][0];
      b4[i] = *(const float4*)&wt[k4][tx + 16 * i][0];
    }
#pragma unroll
    for (int r = 0; r < 4; ++r)
#pragma unroll
      for (int c = 0; c < 4; ++c) {
        acc[r][c] = fmaf(a4[r].x, b4[c].x, acc[r][c]);
        acc[r][c] = fmaf(a4[r].y, b4[c].y, acc[r][c]);
        acc[r][c] = fmaf(a4[r].z, b4[c].z, acc[r][c]);
        acc[r][c] = fmaf(a4[r].w, b4[c].w, acc[r][c]);
      }
  }

#pragma unroll
  for (int r = 0; r < 4; ++r) {
    int R = row0 + ty + 16 * r;
#pragma unroll
    for (int c = 0; c < 4; ++c) {
      int col = col0 + tx + 16 * c;
      if (col < DI)
        xc[(size_t)R * DI + col] = acc[r][c];
      else
        zbuf[(size_t)R * DI + (col - DI)] = acc[r][c];
    }
  }
}

// ---------------------------------------------------------------------------
// Kernel 2: depthwise 3x3 conv (SAME) + bias + SiLU.  layout [b][l][d].
// ---------------------------------------------------------------------------
__global__ __launch_bounds__(256) void k_conv(const float* __restrict__ xc,
                                              const float* __restrict__ cw,
                                              const float* __restrict__ cbias,
                                              float* __restrict__ xf) {
  int gid = blockIdx.x * 256 + threadIdx.x;
  int d = gid % DI;
  int bl = gid / DI;
  int l = bl % LL;
  int b = bl / LL;
  int hh = l >> 8, ww = l & 255;
  float acc = 0.f;
#pragma unroll
  for (int dh = -1; dh <= 1; ++dh) {
    int h2 = hh + dh;
    if (h2 < 0 || h2 >= Hh) continue;
#pragma unroll
    for (int dw = -1; dw <= 1; ++dw) {
      int w2 = ww + dw;
      if (w2 < 0 || w2 >= Wd) continue;
      acc = fmaf(xc[((size_t)b * LL + (h2 << 8) + w2) * DI + d],
                 cw[d * 9 + (dh + 1) * 3 + (dw + 1)], acc);
    }
  }
  float v = acc + cbias[d];
  xf[gid] = v * sigmoidf_(v);
}

// ---------------------------------------------------------------------------
// Kernel 3: x_dbl projections into padded rows [b][k][l][40].
// ---------------------------------------------------------------------------
__global__ __launch_bounds__(256) void k_proj(const float* __restrict__ xf,
                                              const float* __restrict__ xpw,
                                              float* __restrict__ proj) {
  __shared__ float xs[32][193];
  const int bidx = blockIdx.x;
  const int b = bidx >> 8;
  const int l0 = (bidx & 255) * 32;
  const int tid = threadIdx.x;

  for (int idx = tid; idx < 32 * DI; idx += 256) {
    int l = idx / DI, d = idx % DI;
    xs[l][d] = xf[((size_t)b * LL + l0 + l) * DI + d];
  }
  __syncthreads();

  const int lt = tid & 31, j = tid >> 5;
  for (int kc = j; kc < 2 * 38; kc += 8) {
    int k = kc / 38, c = kc % 38;
    const float* wp = xpw + (size_t)(k * 38 + c) * DI;
    float acc = 0.f;
#pragma unroll 8
    for (int d = 0; d < DI; ++d) acc = fmaf(xs[lt][d], wp[d], acc);
    int off = c < 6 ? c : c + 2;
    proj[((size_t)(b * Kk + k) * LL + l0 + lt) * PROJ_C + off] = acc;
  }
}

// ---------------------------------------------------------------------------
// Kernel 4: delta[b,k,l,d] = softplus(dts_r . dtw + bias).  Hoists the
// per-step 6-FMA dot + softplus out of BOTH scan passes.
// ---------------------------------------------------------------------------
__global__ __launch_bounds__(256) void k_delta(const float* __restrict__ proj,
                                               const float* __restrict__ dtw_,
                                               const float* __restrict__ dtb_,
                                               float* __restrict__ delta) {
  int gid = blockIdx.x * 256 + threadIdx.x;  // ((bk*LL + l)*DI + d)
  int d = gid % DI;
  int rem = gid / DI;
  int l = rem % LL;
  int bk = rem / LL;
  int k = bk & 1;
  int kd = k * DI + d;
  const float* pr = proj + (size_t)(bk * LL + l) * PROJ_C;
  const float* w6 = dtw_ + (size_t)kd * 6;
  float draw = dtb_[kd];
#pragma unroll
  for (int r = 0; r < 6; ++r) draw = fmaf(pr[r], w6[r], draw);
  delta[gid] = softplusf_(draw);
}

// ---------------------------------------------------------------------------
// Scan kernels, templated on pass and direction (KD = k). 4 lanes x 4 states
// per d. PASS 1: h from 0 -> hend, P=exp(A*sum d). PASS 3: h from hinit,
// emit y[b,d,l] (KD=0 stores, KD=1 accumulates; reversal folded into index).
// ---------------------------------------------------------------------------
template <int PASS, int KD>
__global__ __launch_bounds__(256) void k_scan(
    const float* __restrict__ delta, const float* __restrict__ proj,
    const float* __restrict__ xf, const float* __restrict__ Alog,
    const float* __restrict__ Dsv, const float* __restrict__ hinit,
    float* __restrict__ hend, float* __restrict__ Pst,
    float* __restrict__ yout) {
  const int tid = threadIdx.x;
  const int sub = tid & 3, gi = tid >> 2;
  int rest = blockIdx.x;
  const int dt3 = rest % 3;  rest /= 3;
  const int g = rest % G;
  const int b = rest / G;
  const int d = dt3 * 64 + gi;
  const int kd = KD * DI + d;
  const int bk = b * Kk + KD;

  float A[4];
#pragma unroll
  for (int i = 0; i < 4; ++i) A[i] = -__expf(Alog[kd * 16 + sub * 4 + i]);

  const size_t gidx = (((size_t)(bk * G + g)) * DI + d) * Nn + sub * 4;
  float h[4];
  if (PASS == 1) {
    h[0] = h[1] = h[2] = h[3] = 0.f;
  } else {
    float4 h4 = *(const float4*)&hinit[gidx];
    h[0] = h4.x; h[1] = h4.y; h[2] = h4.z; h[3] = h4.w;
  }
  const float Dv = (PASS == 3) ? Dsv[kd] : 0.f;

  constexpr int STP = KD ? -1 : 1;
  const int l_start = KD ? (LL - 1 - g * CH) : (g * CH);
  const float* dp = delta + ((size_t)bk * LL + l_start) * DI + d;
  const float* up = xf + ((size_t)b * LL + l_start) * DI + d;
  const float* pp = proj + ((size_t)bk * LL + l_start) * PROJ_C + 8 + sub * 4;
  const size_t ybase = ((size_t)b * DI + d) * LL;

  float dsum = 0.f, ybuf = 0.f;
#pragma unroll 4
  for (int t = 0; t < CH; ++t) {
    const float dlt = *dp;
    const float u = *up;
    const float4 Bv = *(const float4*)pp;
    const float du = dlt * u;
    if (PASS == 1) {
#pragma unroll
      for (int i = 0; i < 4; ++i)
        h[i] = fmaf(__expf(dlt * A[i]), h[i], du * ((const float*)&Bv)[i]);
      dsum += dlt;
    } else {
      const float4 Cv = *(const float4*)(pp + 16);
      float yp = 0.f;
#pragma unroll
      for (int i = 0; i < 4; ++i) {
        h[i] = fmaf(__expf(dlt * A[i]), h[i], du * ((const float*)&Bv)[i]);
        yp = fmaf(h[i], ((const float*)&Cv)[i], yp);
      }
      yp += __shfl_xor(yp, 1, 64);
      yp += __shfl_xor(yp, 2, 64);
      const float yt = fmaf(u, Dv, yp);
      ybuf = ((t & 3) == sub) ? yt : ybuf;
      if ((t & 3) == 3) {
        const int tau = g * CH + (t & ~3) + sub;
        const int lp = KD ? (LL - 1 - tau) : tau;
        if (KD == 0)
          yout[ybase + lp] = ybuf;
        else
          yout[ybase + lp] += ybuf;  // k=0 pass already wrote; stream-ordered
      }
    }
    dp += STP * DI; up += STP * DI; pp += STP * PROJ_C;
  }
  if (PASS == 1) {
    float4 hv = make_float4(h[0], h[1], h[2], h[3]);
    float4 pv = make_float4(__expf(A[0] * dsum), __expf(A[1] * dsum),
                            __expf(A[2] * dsum), __expf(A[3] * dsum));
    *(float4*)&hend[gidx] = hv;
    *(float4*)&Pst[gidx] = pv;
  }
}

// Pass 2: combine chunk summaries sequentially per (b,k,d,n).
__global__ __launch_bounds__(256) void k_scan2(const float* __restrict__ hend,
                                               const float* __restrict__ Pst,
                                               float* __restrict__ hini) {
  int idx = blockIdx.x * 256 + threadIdx.x;
  int n = idx & 15;
  int rem = idx >> 4;
  int d = rem % DI;
  int bk = rem / DI;
  float carry = 0.f;
  for (int g = 0; g < G; ++g) {
    size_t a = (((size_t)(bk * G + g)) * DI + d) * Nn + n;
    float hv = hend[a], pv = Pst[a];
    hini[a] = carry;
    carry = fmaf(pv, carry, hv);
  }
}

// ---------------------------------------------------------------------------
// Kernel 7: out[b,l,c] = sum_d y[b,d,l] * silu(z[b,l,d]) * Wout[c,d]
// ---------------------------------------------------------------------------
__global__ __launch_bounds__(256) void k_out(const float* __restrict__ y,
                                             const float* __restrict__ zbuf,
                                             const float* __restrict__ Wout,
                                             float* __restrict__ out) {
  __shared__ float zt[32][193];
  __shared__ float mt[DI][33];
  const int bidx = blockIdx.x;
  const int b = bidx >> 8;
  const int l0 = (bidx & 255) * 32;
  const int tid = threadIdx.x;

  for (int idx = tid; idx < 32 * DI; idx += 256) {
    int l = idx / DI, d = idx % DI;
    zt[l][d] = zbuf[((size_t)b * LL + l0 + l) * DI + d];
  }
  __syncthreads();

  for (int idx = tid; idx < DI * 32; idx += 256) {
    int d = idx >> 5, l = idx & 31;
    float yv = y[((size_t)b * DI + d) * LL + l0 + l];
    float zv = zt[l][d];
    mt[d][l] = yv * (zv * sigmoidf_(zv));
  }
  __syncthreads();

  const int lt = tid & 31, j = tid >> 5;
  float res[12];
#pragma unroll
  for (int ci = 0; ci < 12; ++ci) {
    int c = j + ci * 8;
    const float* wp = Wout + (size_t)c * DI;
    float acc = 0.f;
#pragma unroll 8
    for (int d = 0; d < DI; ++d) acc = fmaf(mt[d][lt], wp[d], acc);
    res[ci] = acc;
  }
  __syncthreads();
#pragma unroll
  for (int ci = 0; ci < 12; ++ci) zt[lt][j + ci * 8] = res[ci];
  __syncthreads();
  for (int idx = tid; idx < 32 * 96; idx += 256) {
    int l = idx / 96, c = idx % 96;
    out[((size_t)b * LL + l0 + l) * 96 + c] = zt[l][c];
  }
}

// ---------------------------------------------------------------------------
extern "C" void kernel_launch(void* const* d_in, const int* in_sizes, int n_in,
                              void* d_out, int out_size, void* d_ws,
                              size_t ws_size, hipStream_t stream) {
  const float* x    = (const float*)d_in[0];
  const float* Win  = (const float*)d_in[1];
  const float* cw   = (const float*)d_in[2];
  const float* cb   = (const float*)d_in[3];
  const float* xpw  = (const float*)d_in[4];
  const float* dtw  = (const float*)d_in[5];
  const float* dtb  = (const float*)d_in[6];
  const float* Alog = (const float*)d_in[7];
  const float* Dsv  = (const float*)d_in[8];
  const float* Wout = (const float*)d_in[9];
  float* out = (float*)d_out;

  float* ws = (float*)d_ws;
  size_t o = 0;
  float* zbuf  = ws + o;  o += (size_t)ROWS * DI;                 // 25.2 MB
  float* xf    = ws + o;  o += (size_t)ROWS * DI;                 // 25.2 MB
  float* proj  = ws + o;  o += (size_t)Bb * Kk * LL * PROJ_C;     // 10.5 MB
  float* delta = ws + o;  o += (size_t)Bb * Kk * LL * DI;         // 50.3 MB
  const size_t hsz = (size_t)Bb * Kk * G * DI * Nn;               // 1.57M
  float* hend = ws + o;  o += hsz;
  float* Pst  = ws + o;  o += hsz;
  float* hini = ws + o;  o += hsz;
  float* y    = ws + o;  o += (size_t)Bb * DI * LL;               // 25.2 MB
  float* xc   = y;  // alias: xc dead after conv, before y is written

  k_xz<<<dim3(ROWS / 64, 6), 256, 0, stream>>>(x, Win, xc, zbuf);
  k_conv<<<dim3((ROWS * DI) / 256), 256, 0, stream>>>(xc, cw, cb, xf);
  k_proj<<<dim3(Bb * (LL / 32)), 256, 0, stream>>>(xf, xpw, proj);
  k_delta<<<dim3((Bb * Kk * LL * DI) / 256), 256, 0, stream>>>(proj, dtw, dtb,
                                                               delta);
  k_scan<1, 0><<<dim3(Bb * G * 3), 256, 0, stream>>>(
      delta, proj, xf, Alog, Dsv, nullptr, hend, Pst, nullptr);
  k_scan<1, 1><<<dim3(Bb * G * 3), 256, 0, stream>>>(
      delta, proj, xf, Alog, Dsv, nullptr, hend, Pst, nullptr);
  k_scan2<<<dim3((Bb * Kk * DI * Nn) / 256), 256, 0, stream>>>(hend, Pst,
                                                               hini);
  k_scan<3, 0><<<dim3(Bb * G * 3), 256, 0, stream>>>(
      delta, proj, xf, Alog, Dsv, hini, nullptr, nullptr, y);
  k_scan<3, 1><<<dim3(Bb * G * 3), 256, 0, stream>>>(
      delta, proj, xf, Alog, Dsv, hini, nullptr, nullptr, y);
  k_out<<<dim3(Bb * (LL / 32)), 256, 0, stream>>>(y, zbuf, Wout, out);
}

// Round 3
// 430.486 us; speedup vs baseline: 1.9226x; 1.1616x over previous
//
#include <hip/hip_runtime.h>

// Problem constants
constexpr int Bb = 4, Hh = 32, Wd = 256, Cc = 96;
constexpr int DI = 192, Nn = 16, Rr = 6, Kk = 2;
constexpr int LL = Hh * Wd;          // 8192
constexpr int ROWS = Bb * LL;        // 32768
constexpr int PROJ_C = 40;           // [0..5]=dts, pad, [8..23]=B, [24..39]=C
constexpr int G = 64;                // scan chunks
constexpr int CH = LL / G;           // 128 steps per chunk

static __device__ __forceinline__ float sigmoidf_(float v) {
  return 1.f / (1.f + __expf(-v));
}
static __device__ __forceinline__ float softplusf_(float v) {
  return v > 20.f ? v : __logf(1.f + __expf(v));
}

// ---------------------------------------------------------------------------
// Kernel 1: xz = x @ W_in^T  (32768 x 384, K=96). 64x64 tile, 4x4 reg tile.
// ---------------------------------------------------------------------------
__global__ __launch_bounds__(256) void k_xz(const float* __restrict__ x,
                                            const float* __restrict__ Win,
                                            float* __restrict__ xc,
                                            float* __restrict__ zbuf) {
  __shared__ float xt[24][66][4];
  __shared__ float wt[24][66][4];
  const int row0 = blockIdx.x * 64;
  const int col0 = blockIdx.y * 64;
  const int tid = threadIdx.x;

  for (int idx = tid; idx < 64 * 96; idx += 256) {
    int r = idx / 96, kkk = idx % 96;
    xt[kkk >> 2][r][kkk & 3] = x[(size_t)(row0 + r) * 96 + kkk];
    wt[kkk >> 2][r][kkk & 3] = Win[(size_t)(col0 + r) * 96 + kkk];
  }
  __syncthreads();

  const int tx = tid & 15, ty = tid >> 4;
  float acc[4][4] = {};
  for (int k4 = 0; k4 < 24; ++k4) {
    float4 a4[4], b4[4];
#pragma unroll
    for (int i = 0; i < 4; ++i) {
      a4[i] = *(const float4*)&xt[k4][ty + 16 * i][0];
      b4[i] = *(const float4*)&wt[k4][tx + 16 * i][0];
    }
#pragma unroll
    for (int r = 0; r < 4; ++r)
#pragma unroll
      for (int c = 0; c < 4; ++c) {
        acc[r][c] = fmaf(a4[r].x, b4[c].x, acc[r][c]);
        acc[r][c] = fmaf(a4[r].y, b4[c].y, acc[r][c]);
        acc[r][c] = fmaf(a4[r].z, b4[c].z, acc[r][c]);
        acc[r][c] = fmaf(a4[r].w, b4[c].w, acc[r][c]);
      }
  }

#pragma unroll
  for (int r = 0; r < 4; ++r) {
    int R = row0 + ty + 16 * r;
#pragma unroll
    for (int c = 0; c < 4; ++c) {
      int col = col0 + tx + 16 * c;
      if (col < DI)
        xc[(size_t)R * DI + col] = acc[r][c];
      else
        zbuf[(size_t)R * DI + (col - DI)] = acc[r][c];
    }
  }
}

// ---------------------------------------------------------------------------
// Kernel 2: depthwise 3x3 conv (SAME) + bias + SiLU, float4 over d.
// ---------------------------------------------------------------------------
__global__ __launch_bounds__(256) void k_conv(const float* __restrict__ xc,
                                              const float* __restrict__ cw,
                                              const float* __restrict__ cbias,
                                              float* __restrict__ xf) {
  int gid = blockIdx.x * 256 + threadIdx.x;  // over ROWS * 48
  int d4 = gid % 48;
  int bl = gid / 48;
  int l = bl % LL;
  int b = bl / LL;
  int hh = l >> 8, ww = l & 255;
  const int d0 = d4 * 4;
  float4 acc = make_float4(0.f, 0.f, 0.f, 0.f);
#pragma unroll
  for (int dh = -1; dh <= 1; ++dh) {
    int h2 = hh + dh;
    if (h2 < 0 || h2 >= Hh) continue;
#pragma unroll
    for (int dw = -1; dw <= 1; ++dw) {
      int w2 = ww + dw;
      if (w2 < 0 || w2 >= Wd) continue;
      const float4 xv =
          *(const float4*)&xc[((size_t)b * LL + (h2 << 8) + w2) * DI + d0];
      const int wi = (dh + 1) * 3 + (dw + 1);
      acc.x = fmaf(xv.x, cw[(d0 + 0) * 9 + wi], acc.x);
      acc.y = fmaf(xv.y, cw[(d0 + 1) * 9 + wi], acc.y);
      acc.z = fmaf(xv.z, cw[(d0 + 2) * 9 + wi], acc.z);
      acc.w = fmaf(xv.w, cw[(d0 + 3) * 9 + wi], acc.w);
    }
  }
  float4 r;
  float v;
  v = acc.x + cbias[d0 + 0]; r.x = v * sigmoidf_(v);
  v = acc.y + cbias[d0 + 1]; r.y = v * sigmoidf_(v);
  v = acc.z + cbias[d0 + 2]; r.z = v * sigmoidf_(v);
  v = acc.w + cbias[d0 + 3]; r.w = v * sigmoidf_(v);
  *(float4*)&xf[((size_t)b * LL + l) * DI + d0] = r;
}

// ---------------------------------------------------------------------------
// Kernel 3: x_dbl projections into padded rows [b][k][l][40].
// ---------------------------------------------------------------------------
__global__ __launch_bounds__(256) void k_proj(const float* __restrict__ xf,
                                              const float* __restrict__ xpw,
                                              float* __restrict__ proj) {
  __shared__ float xs[32][193];
  const int bidx = blockIdx.x;
  const int b = bidx >> 8;
  const int l0 = (bidx & 255) * 32;
  const int tid = threadIdx.x;

  for (int idx = tid; idx < 32 * DI; idx += 256) {
    int l = idx / DI, d = idx % DI;
    xs[l][d] = xf[((size_t)b * LL + l0 + l) * DI + d];
  }
  __syncthreads();

  const int lt = tid & 31, j = tid >> 5;
  for (int kc = j; kc < 2 * 38; kc += 8) {
    int k = kc / 38, c = kc % 38;
    const float* wp = xpw + (size_t)(k * 38 + c) * DI;
    float acc = 0.f;
#pragma unroll 8
    for (int d = 0; d < DI; ++d) acc = fmaf(xs[lt][d], wp[d], acc);
    int off = c < 6 ? c : c + 2;
    proj[((size_t)(b * Kk + k) * LL + l0 + lt) * PROJ_C + off] = acc;
  }
}

// ---------------------------------------------------------------------------
// Kernel 4: delta[b,k,l,d] = softplus(dts_r . dtw + bias), float4 over d.
// ---------------------------------------------------------------------------
__global__ __launch_bounds__(256) void k_delta(const float* __restrict__ proj,
                                               const float* __restrict__ dtw_,
                                               const float* __restrict__ dtb_,
                                               float* __restrict__ delta) {
  int gid = blockIdx.x * 256 + threadIdx.x;  // over (bk, l, d4): Bb*Kk*LL*48
  int d4 = gid % 48;
  int rem = gid / 48;
  int l = rem % LL;
  int bk = rem / LL;
  int k = bk & 1;
  const float* pr = proj + (size_t)(bk * LL + l) * PROJ_C;
  float p[6];
#pragma unroll
  for (int r = 0; r < 6; ++r) p[r] = pr[r];
  float4 res;
#pragma unroll
  for (int j = 0; j < 4; ++j) {
    int kd = k * DI + d4 * 4 + j;
    const float* w6 = dtw_ + (size_t)kd * 6;
    float draw = dtb_[kd];
#pragma unroll
    for (int r = 0; r < 6; ++r) draw = fmaf(p[r], w6[r], draw);
    ((float*)&res)[j] = softplusf_(draw);
  }
  *(float4*)&delta[(size_t)(bk * LL + l) * DI + d4 * 4] = res;
}

// ---------------------------------------------------------------------------
// Scan kernels, templated on pass and direction (KD = k). 4 lanes x 4 states
// per d. PASS 1: h from 0 -> hend, P=exp(A*sum d). PASS 3: h from hinit,
// emit y[b,d,l] (KD=0 stores, KD=1 accumulates; reversal folded into index).
// ---------------------------------------------------------------------------
template <int PASS, int KD>
__global__ __launch_bounds__(256) void k_scan(
    const float* __restrict__ delta, const float* __restrict__ proj,
    const float* __restrict__ xf, const float* __restrict__ Alog,
    const float* __restrict__ Dsv, const float* __restrict__ hinit,
    float* __restrict__ hend, float* __restrict__ Pst,
    float* __restrict__ yout) {
  const int tid = threadIdx.x;
  const int sub = tid & 3, gi = tid >> 2;
  int rest = blockIdx.x;
  const int dt3 = rest % 3;  rest /= 3;
  const int g = rest % G;
  const int b = rest / G;
  const int d = dt3 * 64 + gi;
  const int kd = KD * DI + d;
  const int bk = b * Kk + KD;

  float A[4];
#pragma unroll
  for (int i = 0; i < 4; ++i) A[i] = -__expf(Alog[kd * 16 + sub * 4 + i]);

  const size_t gidx = (((size_t)(bk * G + g)) * DI + d) * Nn + sub * 4;
  float h[4];
  if (PASS == 1) {
    h[0] = h[1] = h[2] = h[3] = 0.f;
  } else {
    float4 h4 = *(const float4*)&hinit[gidx];
    h[0] = h4.x; h[1] = h4.y; h[2] = h4.z; h[3] = h4.w;
  }
  const float Dv = (PASS == 3) ? Dsv[kd] : 0.f;

  constexpr int STP = KD ? -1 : 1;
  const int l_start = KD ? (LL - 1 - g * CH) : (g * CH);
  const float* dp = delta + ((size_t)bk * LL + l_start) * DI + d;
  const float* up = xf + ((size_t)b * LL + l_start) * DI + d;
  const float* pp = proj + ((size_t)bk * LL + l_start) * PROJ_C + 8 + sub * 4;
  const size_t ybase = ((size_t)b * DI + d) * LL;

  float dsum = 0.f, ybuf = 0.f;
#pragma unroll 4
  for (int t = 0; t < CH; ++t) {
    const float dlt = *dp;
    const float u = *up;
    const float4 Bv = *(const float4*)pp;
    const float du = dlt * u;
    if (PASS == 1) {
#pragma unroll
      for (int i = 0; i < 4; ++i)
        h[i] = fmaf(__expf(dlt * A[i]), h[i], du * ((const float*)&Bv)[i]);
      dsum += dlt;
    } else {
      const float4 Cv = *(const float4*)(pp + 16);
      float yp = 0.f;
#pragma unroll
      for (int i = 0; i < 4; ++i) {
        h[i] = fmaf(__expf(dlt * A[i]), h[i], du * ((const float*)&Bv)[i]);
        yp = fmaf(h[i], ((const float*)&Cv)[i], yp);
      }
      yp += __shfl_xor(yp, 1, 64);
      yp += __shfl_xor(yp, 2, 64);
      const float yt = fmaf(u, Dv, yp);
      ybuf = ((t & 3) == sub) ? yt : ybuf;
      if ((t & 3) == 3) {
        const int tau = g * CH + (t & ~3) + sub;
        const int lp = KD ? (LL - 1 - tau) : tau;
        if (KD == 0)
          yout[ybase + lp] = ybuf;
        else
          yout[ybase + lp] += ybuf;  // k=0 pass already wrote; stream-ordered
      }
    }
    dp += STP * DI; up += STP * DI; pp += STP * PROJ_C;
  }
  if (PASS == 1) {
    float4 hv = make_float4(h[0], h[1], h[2], h[3]);
    float4 pv = make_float4(__expf(A[0] * dsum), __expf(A[1] * dsum),
                            __expf(A[2] * dsum), __expf(A[3] * dsum));
    *(float4*)&hend[gidx] = hv;
    *(float4*)&Pst[gidx] = pv;
  }
}

// Pass 2: combine chunk summaries sequentially per (b,k,d,n).
__global__ __launch_bounds__(256) void k_scan2(const float* __restrict__ hend,
                                               const float* __restrict__ Pst,
                                               float* __restrict__ hini) {
  int idx = blockIdx.x * 256 + threadIdx.x;
  int n = idx & 15;
  int rem = idx >> 4;
  int d = rem % DI;
  int bk = rem / DI;
  float carry = 0.f;
  for (int g = 0; g < G; ++g) {
    size_t a = (((size_t)(bk * G + g)) * DI + d) * Nn + n;
    float hv = hend[a], pv = Pst[a];
    hini[a] = carry;
    carry = fmaf(pv, carry, hv);
  }
}

// ---------------------------------------------------------------------------
// Kernel 7: out[l,c] = sum_d (y[b,d,l]*silu(z[b,l,d])) * Wout[c,d]
// Register-tiled GEMM: 128l x 96c block tile, K chunked by 32, 4x12 reg tile.
// Gate folded into LDS staging (silu(z) staged d-fast, multiplied by y
// in place l-fast). All global accesses float4.
// ---------------------------------------------------------------------------
__global__ __launch_bounds__(256) void k_out(const float* __restrict__ y,
                                             const float* __restrict__ zbuf,
                                             const float* __restrict__ Wout,
                                             float* __restrict__ out) {
  __shared__ float As[32][132];  // [dk][l] gated activation chunk
  __shared__ float Ws[32][100];  // [dk][c] weight chunk
  const int tid = threadIdx.x;
  const int row0 = blockIdx.x * 128;
  const int b = row0 >> 13;           // / LL
  const int l0 = row0 & (LL - 1);
  const int tx = tid & 7;             // c = tx*12 + 0..11
  const int ty = tid >> 3;            // l = ty*4 + 0..3
  float acc[4][12] = {};

  for (int kc = 0; kc < 6; ++kc) {
    const int d0 = kc * 32;
    __syncthreads();  // previous chunk's compute must finish before restage
    // phase A: silu(z) -> As[dk][l]   (z is [b][l][d], read d-fast)
    for (int v = tid; v < 1024; v += 256) {
      const int l = v >> 3, dk4 = v & 7;
      const float4 zv = *(const float4*)&zbuf[((size_t)b * LL + l0 + l) * DI +
                                              d0 + dk4 * 4];
      As[dk4 * 4 + 0][l] = zv.x * sigmoidf_(zv.x);
      As[dk4 * 4 + 1][l] = zv.y * sigmoidf_(zv.y);
      As[dk4 * 4 + 2][l] = zv.z * sigmoidf_(zv.z);
      As[dk4 * 4 + 3][l] = zv.w * sigmoidf_(zv.w);
    }
    // stage W chunk (Wout is [c][d], read d-fast)
    for (int v = tid; v < 768; v += 256) {
      const int c = v >> 3, dk4 = v & 7;
      const float4 wv = *(const float4*)&Wout[(size_t)c * DI + d0 + dk4 * 4];
      Ws[dk4 * 4 + 0][c] = wv.x;
      Ws[dk4 * 4 + 1][c] = wv.y;
      Ws[dk4 * 4 + 2][c] = wv.z;
      Ws[dk4 * 4 + 3][c] = wv.w;
    }
    __syncthreads();
    // phase B: gate with y (y is [b][d][l], read l-fast), in-place
    for (int v = tid; v < 1024; v += 256) {
      const int dk = v >> 5, l4 = v & 31;
      const float4 yv =
          *(const float4*)&y[((size_t)b * DI + d0 + dk) * LL + l0 + l4 * 4];
      As[dk][l4 * 4 + 0] *= yv.x;
      As[dk][l4 * 4 + 1] *= yv.y;
      As[dk][l4 * 4 + 2] *= yv.z;
      As[dk][l4 * 4 + 3] *= yv.w;
    }
    __syncthreads();
    // compute: 32 k-steps, 48 FMA per 4 ds_read_b128
    for (int dk = 0; dk < 32; ++dk) {
      const float4 a4 = *(const float4*)&As[dk][ty * 4];
      const float4 w0 = *(const float4*)&Ws[dk][tx * 12];
      const float4 w1 = *(const float4*)&Ws[dk][tx * 12 + 4];
      const float4 w2 = *(const float4*)&Ws[dk][tx * 12 + 8];
      const float av[4] = {a4.x, a4.y, a4.z, a4.w};
      const float wv[12] = {w0.x, w0.y, w0.z, w0.w, w1.x, w1.y,
                            w1.z, w1.w, w2.x, w2.y, w2.z, w2.w};
#pragma unroll
      for (int i = 0; i < 4; ++i)
#pragma unroll
        for (int j = 0; j < 12; ++j)
          acc[i][j] = fmaf(av[i], wv[j], acc[i][j]);
    }
  }

#pragma unroll
  for (int i = 0; i < 4; ++i) {
    float* op = out + ((size_t)b * LL + l0 + ty * 4 + i) * 96 + tx * 12;
    *(float4*)(op + 0) = make_float4(acc[i][0], acc[i][1], acc[i][2], acc[i][3]);
    *(float4*)(op + 4) = make_float4(acc[i][4], acc[i][5], acc[i][6], acc[i][7]);
    *(float4*)(op + 8) = make_float4(acc[i][8], acc[i][9], acc[i][10], acc[i][11]);
  }
}

// ---------------------------------------------------------------------------
extern "C" void kernel_launch(void* const* d_in, const int* in_sizes, int n_in,
                              void* d_out, int out_size, void* d_ws,
                              size_t ws_size, hipStream_t stream) {
  const float* x    = (const float*)d_in[0];
  const float* Win  = (const float*)d_in[1];
  const float* cw   = (const float*)d_in[2];
  const float* cb   = (const float*)d_in[3];
  const float* xpw  = (const float*)d_in[4];
  const float* dtw  = (const float*)d_in[5];
  const float* dtb  = (const float*)d_in[6];
  const float* Alog = (const float*)d_in[7];
  const float* Dsv  = (const float*)d_in[8];
  const float* Wout = (const float*)d_in[9];
  float* out = (float*)d_out;

  float* ws = (float*)d_ws;
  size_t o = 0;
  float* zbuf  = ws + o;  o += (size_t)ROWS * DI;                 // 25.2 MB
  float* xf    = ws + o;  o += (size_t)ROWS * DI;                 // 25.2 MB
  float* proj  = ws + o;  o += (size_t)Bb * Kk * LL * PROJ_C;     // 10.5 MB
  float* delta = ws + o;  o += (size_t)Bb * Kk * LL * DI;         // 50.3 MB
  const size_t hsz = (size_t)Bb * Kk * G * DI * Nn;               // 1.57M
  float* hend = ws + o;  o += hsz;
  float* Pst  = ws + o;  o += hsz;
  float* hini = ws + o;  o += hsz;
  float* y    = ws + o;  o += (size_t)Bb * DI * LL;               // 25.2 MB
  float* xc   = y;  // alias: xc dead after conv, before y is written

  k_xz<<<dim3(ROWS / 64, 6), 256, 0, stream>>>(x, Win, xc, zbuf);
  k_conv<<<dim3((ROWS * 48) / 256), 256, 0, stream>>>(xc, cw, cb, xf);
  k_proj<<<dim3(Bb * (LL / 32)), 256, 0, stream>>>(xf, xpw, proj);
  k_delta<<<dim3((Bb * Kk * LL * 48) / 256), 256, 0, stream>>>(proj, dtw, dtb,
                                                               delta);
  k_scan<1, 0><<<dim3(Bb * G * 3), 256, 0, stream>>>(
      delta, proj, xf, Alog, Dsv, nullptr, hend, Pst, nullptr);
  k_scan<1, 1><<<dim3(Bb * G * 3), 256, 0, stream>>>(
      delta, proj, xf, Alog, Dsv, nullptr, hend, Pst, nullptr);
  k_scan2<<<dim3((Bb * Kk * DI * Nn) / 256), 256, 0, stream>>>(hend, Pst,
                                                               hini);
  k_scan<3, 0><<<dim3(Bb * G * 3), 256, 0, stream>>>(
      delta, proj, xf, Alog, Dsv, hini, nullptr, nullptr, y);
  k_scan<3, 1><<<dim3(Bb * G * 3), 256, 0, stream>>>(
      delta, proj, xf, Alog, Dsv, hini, nullptr, nullptr, y);
  k_out<<<dim3(ROWS / 128), 256, 0, stream>>>(y, zbuf, Wout, out);
}

// Round 4
// 393.330 us; speedup vs baseline: 2.1042x; 1.0945x over previous
//
#include <hip/hip_runtime.h>

// Problem constants
constexpr int Bb = 4, Hh = 32, Wd = 256, Cc = 96;
constexpr int DI = 192, Nn = 16, Rr = 6, Kk = 2;
constexpr int LL = Hh * Wd;          // 8192
constexpr int ROWS = Bb * LL;        // 32768
constexpr int PROJ_C = 40;           // [0..5]=dts, pad, [8..23]=B, [24..39]=C
constexpr int G = 64;                // scan chunks
constexpr int CH = LL / G;           // 128 steps per chunk

static __device__ __forceinline__ float sigmoidf_(float v) {
  return 1.f / (1.f + __expf(-v));
}
static __device__ __forceinline__ float softplusf_(float v) {
  return v > 20.f ? v : __logf(1.f + __expf(v));
}

// ---------------------------------------------------------------------------
// Kernel 1: xz = x @ W_in^T  (32768 x 384, K=96). 64x64 tile, 4x4 reg tile.
// ---------------------------------------------------------------------------
__global__ __launch_bounds__(256) void k_xz(const float* __restrict__ x,
                                            const float* __restrict__ Win,
                                            float* __restrict__ xc,
                                            float* __restrict__ zbuf) {
  __shared__ float xt[24][66][4];
  __shared__ float wt[24][66][4];
  const int row0 = blockIdx.x * 64;
  const int col0 = blockIdx.y * 64;
  const int tid = threadIdx.x;

  for (int idx = tid; idx < 64 * 96; idx += 256) {
    int r = idx / 96, kkk = idx % 96;
    xt[kkk >> 2][r][kkk & 3] = x[(size_t)(row0 + r) * 96 + kkk];
    wt[kkk >> 2][r][kkk & 3] = Win[(size_t)(col0 + r) * 96 + kkk];
  }
  __syncthreads();

  const int tx = tid & 15, ty = tid >> 4;
  float acc[4][4] = {};
  for (int k4 = 0; k4 < 24; ++k4) {
    float4 a4[4], b4[4];
#pragma unroll
    for (int i = 0; i < 4; ++i) {
      a4[i] = *(const float4*)&xt[k4][ty + 16 * i][0];
      b4[i] = *(const float4*)&wt[k4][tx + 16 * i][0];
    }
#pragma unroll
    for (int r = 0; r < 4; ++r)
#pragma unroll
      for (int c = 0; c < 4; ++c) {
        acc[r][c] = fmaf(a4[r].x, b4[c].x, acc[r][c]);
        acc[r][c] = fmaf(a4[r].y, b4[c].y, acc[r][c]);
        acc[r][c] = fmaf(a4[r].z, b4[c].z, acc[r][c]);
        acc[r][c] = fmaf(a4[r].w, b4[c].w, acc[r][c]);
      }
  }

#pragma unroll
  for (int r = 0; r < 4; ++r) {
    int R = row0 + ty + 16 * r;
#pragma unroll
    for (int c = 0; c < 4; ++c) {
      int col = col0 + tx + 16 * c;
      if (col < DI)
        xc[(size_t)R * DI + col] = acc[r][c];
      else
        zbuf[(size_t)R * DI + (col - DI)] = acc[r][c];
    }
  }
}

// ---------------------------------------------------------------------------
// Kernel 2: depthwise 3x3 conv (SAME) + bias + SiLU, float4 over d.
// ---------------------------------------------------------------------------
__global__ __launch_bounds__(256) void k_conv(const float* __restrict__ xc,
                                              const float* __restrict__ cw,
                                              const float* __restrict__ cbias,
                                              float* __restrict__ xf) {
  int gid = blockIdx.x * 256 + threadIdx.x;  // over ROWS * 48
  int d4 = gid % 48;
  int bl = gid / 48;
  int l = bl % LL;
  int b = bl / LL;
  int hh = l >> 8, ww = l & 255;
  const int d0 = d4 * 4;
  float4 acc = make_float4(0.f, 0.f, 0.f, 0.f);
#pragma unroll
  for (int dh = -1; dh <= 1; ++dh) {
    int h2 = hh + dh;
    if (h2 < 0 || h2 >= Hh) continue;
#pragma unroll
    for (int dw = -1; dw <= 1; ++dw) {
      int w2 = ww + dw;
      if (w2 < 0 || w2 >= Wd) continue;
      const float4 xv =
          *(const float4*)&xc[((size_t)b * LL + (h2 << 8) + w2) * DI + d0];
      const int wi = (dh + 1) * 3 + (dw + 1);
      acc.x = fmaf(xv.x, cw[(d0 + 0) * 9 + wi], acc.x);
      acc.y = fmaf(xv.y, cw[(d0 + 1) * 9 + wi], acc.y);
      acc.z = fmaf(xv.z, cw[(d0 + 2) * 9 + wi], acc.z);
      acc.w = fmaf(xv.w, cw[(d0 + 3) * 9 + wi], acc.w);
    }
  }
  float4 r;
  float v;
  v = acc.x + cbias[d0 + 0]; r.x = v * sigmoidf_(v);
  v = acc.y + cbias[d0 + 1]; r.y = v * sigmoidf_(v);
  v = acc.z + cbias[d0 + 2]; r.z = v * sigmoidf_(v);
  v = acc.w + cbias[d0 + 3]; r.w = v * sigmoidf_(v);
  *(float4*)&xf[((size_t)b * LL + l) * DI + d0] = r;
}

// ---------------------------------------------------------------------------
// Kernel 3: x_dbl projections. Register-tiled GEMM: M=ROWS (b,l), N=80
// (2k x 40 padded slots; pad slots 6,7 get zero weights), K=192 in chunks
// of 32. 64l x 80s block tile, 4x5 reg tile. Results staged via LDS for
// coalesced float4 writes of contiguous proj rows.
// ---------------------------------------------------------------------------
__global__ __launch_bounds__(256) void k_proj(const float* __restrict__ xf,
                                              const float* __restrict__ xpw,
                                              float* __restrict__ proj) {
  __shared__ float smem[5376];     // As[32][68] | Ws[32][84]; reused as res[64][84]
  float* As = smem;                // [dk][l], row stride 68
  float* Ws = smem + 32 * 68;      // [dk][s], row stride 84
  const int tid = threadIdx.x;
  const int row0 = blockIdx.x * 64;
  const int b = row0 >> 13;
  const int l0 = row0 & (LL - 1);
  const int tx = tid & 15;         // s = tx*5 + j
  const int ty = tid >> 4;         // l = ty*4 + i
  float acc[4][5] = {};

  for (int kc = 0; kc < 6; ++kc) {
    const int d0 = kc * 32;
    __syncthreads();
    // stage As[dk][l] from xf ([b][l][d], d-fast float4)
    for (int v = tid; v < 512; v += 256) {
      const int l = v >> 3, dk4 = v & 7;
      const float4 xv =
          *(const float4*)&xf[((size_t)b * LL + l0 + l) * DI + d0 + dk4 * 4];
      As[(dk4 * 4 + 0) * 68 + l] = xv.x;
      As[(dk4 * 4 + 1) * 68 + l] = xv.y;
      As[(dk4 * 4 + 2) * 68 + l] = xv.z;
      As[(dk4 * 4 + 3) * 68 + l] = xv.w;
    }
    // stage Ws[dk][s] from xpw ([k][38][192], d-fast float4); pads -> 0
    for (int v = tid; v < 640; v += 256) {
      const int s = v >> 3, dk4 = v & 7;
      const int k = s / 40, off = s % 40;
      float4 wv = make_float4(0.f, 0.f, 0.f, 0.f);
      if (off < 6 || off >= 8) {
        const int c = off < 6 ? off : off - 2;
        wv = *(const float4*)&xpw[(size_t)(k * 38 + c) * DI + d0 + dk4 * 4];
      }
      Ws[(dk4 * 4 + 0) * 84 + s] = wv.x;
      Ws[(dk4 * 4 + 1) * 84 + s] = wv.y;
      Ws[(dk4 * 4 + 2) * 84 + s] = wv.z;
      Ws[(dk4 * 4 + 3) * 84 + s] = wv.w;
    }
    __syncthreads();
    for (int dk = 0; dk < 32; ++dk) {
      const float4 a4 = *(const float4*)&As[dk * 68 + ty * 4];
      float w[5];
#pragma unroll
      for (int j = 0; j < 5; ++j) w[j] = Ws[dk * 84 + tx * 5 + j];
      const float av[4] = {a4.x, a4.y, a4.z, a4.w};
#pragma unroll
      for (int i = 0; i < 4; ++i)
#pragma unroll
        for (int j = 0; j < 5; ++j)
          acc[i][j] = fmaf(av[i], w[j], acc[i][j]);
    }
  }

  __syncthreads();
  float* res = smem;  // [64][84]
#pragma unroll
  for (int i = 0; i < 4; ++i)
#pragma unroll
    for (int j = 0; j < 5; ++j)
      res[(ty * 4 + i) * 84 + tx * 5 + j] = acc[i][j];
  __syncthreads();
#pragma unroll
  for (int k = 0; k < 2; ++k) {
    float* dst = proj + ((size_t)(b * Kk + k) * LL + l0) * PROJ_C;
    for (int v = tid; v < 640; v += 256) {
      const int l = v / 10, q = v % 10;
      *(float4*)&dst[l * PROJ_C + q * 4] =
          *(const float4*)&res[l * 84 + k * 40 + q * 4];
    }
  }
}

// ---------------------------------------------------------------------------
// Kernel 4: delta[b,k,l,d] = softplus(dts_r . dtw + bias), float4 over d.
// ---------------------------------------------------------------------------
__global__ __launch_bounds__(256) void k_delta(const float* __restrict__ proj,
                                               const float* __restrict__ dtw_,
                                               const float* __restrict__ dtb_,
                                               float* __restrict__ delta) {
  int gid = blockIdx.x * 256 + threadIdx.x;  // over (bk, l, d4): Bb*Kk*LL*48
  int d4 = gid % 48;
  int rem = gid / 48;
  int l = rem % LL;
  int bk = rem / LL;
  int k = bk & 1;
  const float* pr = proj + (size_t)(bk * LL + l) * PROJ_C;
  float p[6];
#pragma unroll
  for (int r = 0; r < 6; ++r) p[r] = pr[r];
  float4 res;
#pragma unroll
  for (int j = 0; j < 4; ++j) {
    int kd = k * DI + d4 * 4 + j;
    const float* w6 = dtw_ + (size_t)kd * 6;
    float draw = dtb_[kd];
#pragma unroll
    for (int r = 0; r < 6; ++r) draw = fmaf(p[r], w6[r], draw);
    ((float*)&res)[j] = softplusf_(draw);
  }
  *(float4*)&delta[(size_t)(bk * LL + l) * DI + d4 * 4] = res;
}

// ---------------------------------------------------------------------------
// Scan kernels, templated on pass and direction (KD = k). 4 lanes x 4 states
// per d. PASS 1: h from 0 -> hend, P=exp(A*sum d). PASS 3: h from hinit,
// emit y[b,d,l] (KD=0 stores, KD=1 accumulates; reversal folded into index).
// ---------------------------------------------------------------------------
template <int PASS, int KD>
__global__ __launch_bounds__(256) void k_scan(
    const float* __restrict__ delta, const float* __restrict__ proj,
    const float* __restrict__ xf, const float* __restrict__ Alog,
    const float* __restrict__ Dsv, const float* __restrict__ hinit,
    float* __restrict__ hend, float* __restrict__ Pst,
    float* __restrict__ yout) {
  const int tid = threadIdx.x;
  const int sub = tid & 3, gi = tid >> 2;
  int rest = blockIdx.x;
  const int dt3 = rest % 3;  rest /= 3;
  const int g = rest % G;
  const int b = rest / G;
  const int d = dt3 * 64 + gi;
  const int kd = KD * DI + d;
  const int bk = b * Kk + KD;

  float A[4];
#pragma unroll
  for (int i = 0; i < 4; ++i) A[i] = -__expf(Alog[kd * 16 + sub * 4 + i]);

  const size_t gidx = (((size_t)(bk * G + g)) * DI + d) * Nn + sub * 4;
  float h[4];
  if (PASS == 1) {
    h[0] = h[1] = h[2] = h[3] = 0.f;
  } else {
    float4 h4 = *(const float4*)&hinit[gidx];
    h[0] = h4.x; h[1] = h4.y; h[2] = h4.z; h[3] = h4.w;
  }
  const float Dv = (PASS == 3) ? Dsv[kd] : 0.f;

  constexpr int STP = KD ? -1 : 1;
  const int l_start = KD ? (LL - 1 - g * CH) : (g * CH);
  const float* dp = delta + ((size_t)bk * LL + l_start) * DI + d;
  const float* up = xf + ((size_t)b * LL + l_start) * DI + d;
  const float* pp = proj + ((size_t)bk * LL + l_start) * PROJ_C + 8 + sub * 4;
  const size_t ybase = ((size_t)b * DI + d) * LL;

  float dsum = 0.f, ybuf = 0.f;
#pragma unroll 4
  for (int t = 0; t < CH; ++t) {
    const float dlt = *dp;
    const float u = *up;
    const float4 Bv = *(const float4*)pp;
    const float du = dlt * u;
    if (PASS == 1) {
#pragma unroll
      for (int i = 0; i < 4; ++i)
        h[i] = fmaf(__expf(dlt * A[i]), h[i], du * ((const float*)&Bv)[i]);
      dsum += dlt;
    } else {
      const float4 Cv = *(const float4*)(pp + 16);
      float yp = 0.f;
#pragma unroll
      for (int i = 0; i < 4; ++i) {
        h[i] = fmaf(__expf(dlt * A[i]), h[i], du * ((const float*)&Bv)[i]);
        yp = fmaf(h[i], ((const float*)&Cv)[i], yp);
      }
      yp += __shfl_xor(yp, 1, 64);
      yp += __shfl_xor(yp, 2, 64);
      const float yt = fmaf(u, Dv, yp);
      ybuf = ((t & 3) == sub) ? yt : ybuf;
      if ((t & 3) == 3) {
        const int tau = g * CH + (t & ~3) + sub;
        const int lp = KD ? (LL - 1 - tau) : tau;
        if (KD == 0)
          yout[ybase + lp] = ybuf;
        else
          yout[ybase + lp] += ybuf;  // k=0 pass already wrote; stream-ordered
      }
    }
    dp += STP * DI; up += STP * DI; pp += STP * PROJ_C;
  }
  if (PASS == 1) {
    float4 hv = make_float4(h[0], h[1], h[2], h[3]);
    float4 pv = make_float4(__expf(A[0] * dsum), __expf(A[1] * dsum),
                            __expf(A[2] * dsum), __expf(A[3] * dsum));
    *(float4*)&hend[gidx] = hv;
    *(float4*)&Pst[gidx] = pv;
  }
}

// Pass 2: combine chunk summaries sequentially per (b,k,d,n).
__global__ __launch_bounds__(256) void k_scan2(const float* __restrict__ hend,
                                               const float* __restrict__ Pst,
                                               float* __restrict__ hini) {
  int idx = blockIdx.x * 256 + threadIdx.x;
  int n = idx & 15;
  int rem = idx >> 4;
  int d = rem % DI;
  int bk = rem / DI;
  float carry = 0.f;
  for (int g = 0; g < G; ++g) {
    size_t a = (((size_t)(bk * G + g)) * DI + d) * Nn + n;
    float hv = hend[a], pv = Pst[a];
    hini[a] = carry;
    carry = fmaf(pv, carry, hv);
  }
}

// ---------------------------------------------------------------------------
// Kernel 7: out[l,c] = sum_d (y[b,d,l]*silu(z[b,l,d])) * Wout[c,d]
// Register-tiled GEMM: 128l x 96c block tile, K chunked by 32, 4x12 reg tile.
// ---------------------------------------------------------------------------
__global__ __launch_bounds__(256) void k_out(const float* __restrict__ y,
                                             const float* __restrict__ zbuf,
                                             const float* __restrict__ Wout,
                                             float* __restrict__ out) {
  __shared__ float As[32][132];  // [dk][l] gated activation chunk
  __shared__ float Ws[32][100];  // [dk][c] weight chunk
  const int tid = threadIdx.x;
  const int row0 = blockIdx.x * 128;
  const int b = row0 >> 13;           // / LL
  const int l0 = row0 & (LL - 1);
  const int tx = tid & 7;             // c = tx*12 + 0..11
  const int ty = tid >> 3;            // l = ty*4 + 0..3
  float acc[4][12] = {};

  for (int kc = 0; kc < 6; ++kc) {
    const int d0 = kc * 32;
    __syncthreads();  // previous chunk's compute must finish before restage
    // phase A: silu(z) -> As[dk][l]   (z is [b][l][d], read d-fast)
    for (int v = tid; v < 1024; v += 256) {
      const int l = v >> 3, dk4 = v & 7;
      const float4 zv = *(const float4*)&zbuf[((size_t)b * LL + l0 + l) * DI +
                                              d0 + dk4 * 4];
      As[dk4 * 4 + 0][l] = zv.x * sigmoidf_(zv.x);
      As[dk4 * 4 + 1][l] = zv.y * sigmoidf_(zv.y);
      As[dk4 * 4 + 2][l] = zv.z * sigmoidf_(zv.z);
      As[dk4 * 4 + 3][l] = zv.w * sigmoidf_(zv.w);
    }
    // stage W chunk (Wout is [c][d], read d-fast)
    for (int v = tid; v < 768; v += 256) {
      const int c = v >> 3, dk4 = v & 7;
      const float4 wv = *(const float4*)&Wout[(size_t)c * DI + d0 + dk4 * 4];
      Ws[dk4 * 4 + 0][c] = wv.x;
      Ws[dk4 * 4 + 1][c] = wv.y;
      Ws[dk4 * 4 + 2][c] = wv.z;
      Ws[dk4 * 4 + 3][c] = wv.w;
    }
    __syncthreads();
    // phase B: gate with y (y is [b][d][l], read l-fast), in-place
    for (int v = tid; v < 1024; v += 256) {
      const int dk = v >> 5, l4 = v & 31;
      const float4 yv =
          *(const float4*)&y[((size_t)b * DI + d0 + dk) * LL + l0 + l4 * 4];
      As[dk][l4 * 4 + 0] *= yv.x;
      As[dk][l4 * 4 + 1] *= yv.y;
      As[dk][l4 * 4 + 2] *= yv.z;
      As[dk][l4 * 4 + 3] *= yv.w;
    }
    __syncthreads();
    // compute: 32 k-steps, 48 FMA per 4 ds_read_b128
    for (int dk = 0; dk < 32; ++dk) {
      const float4 a4 = *(const float4*)&As[dk][ty * 4];
      const float4 w0 = *(const float4*)&Ws[dk][tx * 12];
      const float4 w1 = *(const float4*)&Ws[dk][tx * 12 + 4];
      const float4 w2 = *(const float4*)&Ws[dk][tx * 12 + 8];
      const float av[4] = {a4.x, a4.y, a4.z, a4.w};
      const float wv[12] = {w0.x, w0.y, w0.z, w0.w, w1.x, w1.y,
                            w1.z, w1.w, w2.x, w2.y, w2.z, w2.w};
#pragma unroll
      for (int i = 0; i < 4; ++i)
#pragma unroll
        for (int j = 0; j < 12; ++j)
          acc[i][j] = fmaf(av[i], wv[j], acc[i][j]);
    }
  }

#pragma unroll
  for (int i = 0; i < 4; ++i) {
    float* op = out + ((size_t)b * LL + l0 + ty * 4 + i) * 96 + tx * 12;
    *(float4*)(op + 0) = make_float4(acc[i][0], acc[i][1], acc[i][2], acc[i][3]);
    *(float4*)(op + 4) = make_float4(acc[i][4], acc[i][5], acc[i][6], acc[i][7]);
    *(float4*)(op + 8) = make_float4(acc[i][8], acc[i][9], acc[i][10], acc[i][11]);
  }
}

// ---------------------------------------------------------------------------
extern "C" void kernel_launch(void* const* d_in, const int* in_sizes, int n_in,
                              void* d_out, int out_size, void* d_ws,
                              size_t ws_size, hipStream_t stream) {
  const float* x    = (const float*)d_in[0];
  const float* Win  = (const float*)d_in[1];
  const float* cw   = (const float*)d_in[2];
  const float* cb   = (const float*)d_in[3];
  const float* xpw  = (const float*)d_in[4];
  const float* dtw  = (const float*)d_in[5];
  const float* dtb  = (const float*)d_in[6];
  const float* Alog = (const float*)d_in[7];
  const float* Dsv  = (const float*)d_in[8];
  const float* Wout = (const float*)d_in[9];
  float* out = (float*)d_out;

  float* ws = (float*)d_ws;
  size_t o = 0;
  float* zbuf  = ws + o;  o += (size_t)ROWS * DI;                 // 25.2 MB
  float* xf    = ws + o;  o += (size_t)ROWS * DI;                 // 25.2 MB
  float* proj  = ws + o;  o += (size_t)Bb * Kk * LL * PROJ_C;     // 10.5 MB
  float* delta = ws + o;  o += (size_t)Bb * Kk * LL * DI;         // 50.3 MB
  const size_t hsz = (size_t)Bb * Kk * G * DI * Nn;               // 1.57M
  float* hend = ws + o;  o += hsz;
  float* Pst  = ws + o;  o += hsz;
  float* hini = ws + o;  o += hsz;
  float* y    = ws + o;  o += (size_t)Bb * DI * LL;               // 25.2 MB
  float* xc   = y;  // alias: xc dead after conv, before y is written

  k_xz<<<dim3(ROWS / 64, 6), 256, 0, stream>>>(x, Win, xc, zbuf);
  k_conv<<<dim3((ROWS * 48) / 256), 256, 0, stream>>>(xc, cw, cb, xf);
  k_proj<<<dim3(ROWS / 64), 256, 0, stream>>>(xf, xpw, proj);
  k_delta<<<dim3((Bb * Kk * LL * 48) / 256), 256, 0, stream>>>(proj, dtw, dtb,
                                                               delta);
  k_scan<1, 0><<<dim3(Bb * G * 3), 256, 0, stream>>>(
      delta, proj, xf, Alog, Dsv, nullptr, hend, Pst, nullptr);
  k_scan<1, 1><<<dim3(Bb * G * 3), 256, 0, stream>>>(
      delta, proj, xf, Alog, Dsv, nullptr, hend, Pst, nullptr);
  k_scan2<<<dim3((Bb * Kk * DI * Nn) / 256), 256, 0, stream>>>(hend, Pst,
                                                               hini);
  k_scan<3, 0><<<dim3(Bb * G * 3), 256, 0, stream>>>(
      delta, proj, xf, Alog, Dsv, hini, nullptr, nullptr, y);
  k_scan<3, 1><<<dim3(Bb * G * 3), 256, 0, stream>>>(
      delta, proj, xf, Alog, Dsv, hini, nullptr, nullptr, y);
  k_out<<<dim3(ROWS / 128), 256, 0, stream>>>(y, zbuf, Wout, out);
}